// Round 3
// baseline (3721.291 us; speedup 1.0000x reference)
//
#include <hip/hip_runtime.h>
#include <stdint.h>

#define NBATCH 128
#define NNEUR  4096
#define TLAST  180                      // outputs depend only on steps 0..180
#define DECAY  0.6065306597126334f      // float(exp(-0.5))

// One kernel per time step.
// Grid: 1024 blocks = 128 batches x 8 column tiles (512 cols each); bid = b*8 + tile
// so all blocks of a tile share one XCD (bid % 8 round-robin) -> W slice L2 reuse.
// Block: 256 threads = 4 waves; wave w owns cols [tile*512 + w*128, +128), 2 cols/lane.
// Spike bits: word of batch b at index (n>>7)*2 + (n&1) holds bit (n>>1)&63 for col n.
__global__ __launch_bounds__(256) void lif_step(
    const float* __restrict__ ff, const float* __restrict__ W,
    const float* __restrict__ rec0, float* __restrict__ out,
    float* __restrict__ volts, float* __restrict__ rec,
    float* __restrict__ sum_s, float* __restrict__ sum_v,
    const unsigned long long* __restrict__ bits_old,
    unsigned long long* __restrict__ bits_new, int t)
{
#pragma clang fp contract(off)          // match numpy's separate mul/add roundings
    __shared__ __align__(16) unsigned short slist[NNEUR];
    __shared__ int scnt;

    const int tid  = threadIdx.x;
    const int lane = tid & 63;
    const int wid  = tid >> 6;
    const int bid  = blockIdx.x;
    const int b    = bid >> 3;                        // batch
    const int tile = bid & 7;
    const int c0   = (tile << 9) + (wid << 7);        // wave's 128-col base
    const int n0   = c0 + (lane << 1);                // lane's first col
    const unsigned laneb = (unsigned)n0 * 4u;         // byte offset within a W row

    float accx = 0.f, accy = 0.f;

    if (t > 0) {
        // ---- decode this batch's spike bitmask into an LDS index list (wave 0) ----
        if (wid == 0) {
            unsigned long long m = bits_old[(b << 6) + lane];   // word `lane`
            int c = __popcll(m);
            int x = c;
            #pragma unroll
            for (int o = 1; o < 64; o <<= 1) {
                int y = __shfl_up(x, (unsigned)o);
                if (lane >= o) x += y;
            }
            if (lane == 63) scnt = x;
            int widx = x - c;                                   // exclusive prefix
            const int jb = ((lane >> 1) << 7) + (lane & 1);     // col base of word
            while (m) {
                int u = __builtin_ctzll(m);
                m &= m - 1;
                slist[widx++] = (unsigned short)(jb + (u << 1));
            }
        }
        __syncthreads();

        // ---- sparse gather, 8-deep double-buffered pipeline ----
        const int cnt = scnt;
        const char* Wb = (const char*)W;

        auto load8 = [&](float2* R, int ii) {
            const uint4 pk = *(const uint4*)(slist + ii);
            unsigned q[4];
            q[0] = pk.x; q[1] = pk.y; q[2] = pk.z; q[3] = pk.w;
            #pragma unroll
            for (int k = 0; k < 4; ++k) {
                const unsigned qq = __builtin_amdgcn_readfirstlane(q[k]);
                R[2 * k]     = *(const float2*)(Wb + (((qq & 0xffffu) << 14) + laneb));
                R[2 * k + 1] = *(const float2*)(Wb + (((qq >> 16)     << 14) + laneb));
            }
        };
        auto acc8 = [&](const float2* R) {
            #pragma unroll
            for (int k = 0; k < 8; ++k) { accx += R[k].x; accy += R[k].y; }
        };

        int i = 0;
        if (cnt >= 8) {
            float2 A[8], B[8];
            load8(A, 0); i = 8;
            while (i + 16 <= cnt) {
                load8(B, i);     acc8(A);
                load8(A, i + 8); acc8(B);
                i += 16;
            }
            if (i + 8 <= cnt) { load8(B, i); acc8(A); acc8(B); i += 8; }
            else              { acc8(A); }
        }
        for (; i < cnt; ++i) {
            unsigned q = (unsigned)slist[i];
            q = __builtin_amdgcn_readfirstlane(q);
            const float2 w = *(const float2*)(Wb + ((q << 14) + laneb));
            accx += w.x; accy += w.y;
        }
    }

    // ---- elementwise LIF update (exact numpy op order, no contraction) ----
    const size_t idx = ((size_t)b << 12) + (size_t)n0;

    float2 r2 = (t == 0) ? *(const float2*)(rec0 + idx)
                         : *(const float2*)(rec + idx);
    r2.x = r2.x * DECAY + accx * 0.5f;
    r2.y = r2.y * DECAY + accy * 0.5f;

    const float2 f2 = *(const float2*)(ff + (((size_t)b * 200 + (size_t)t) << 12) + n0);

    float2 v2 = make_float2(0.f, 0.f);
    if (t > 0) v2 = *(const float2*)(volts + idx);
    v2.x = v2.x * DECAY + 0.5f * (f2.x + r2.x);
    v2.y = v2.y * DECAY + 0.5f * (f2.y + r2.y);

    const bool s0 = v2.x >= 1.0f, s1 = v2.y >= 1.0f;
    if (s0) v2.x = 0.f;
    if (s1) v2.y = 0.f;

    *(float2*)(volts + idx) = v2;
    *(float2*)(rec + idx)   = r2;

    // ---- new spike bitmask: raw ballots, 2 words per wave ----
    const unsigned long long m0 = __ballot(s0), m1 = __ballot(s1);
    if (lane == 0) {
        unsigned long long* dst = bits_new + (b << 6) + ((c0 >> 7) << 1);
        dst[0] = m0; dst[1] = m1;
    }

    // ---- recording windows: steps 80..100 -> k0, 101..120 -> k1, ... 161..180 -> k4 ----
    if (t >= 80) {
        const float2 s2 = make_float2(s0 ? 1.f : 0.f, s1 ? 1.f : 0.f);
        const bool start = (t == 80) || (t == 101) || (t == 121) || (t == 141) || (t == 161);
        float2 ss, sv;
        if (start) {
            ss = s2; sv = v2;
        } else {
            ss = *(const float2*)(sum_s + idx);
            sv = *(const float2*)(sum_v + idx);
            ss.x += s2.x; ss.y += s2.y;
            sv.x += v2.x; sv.y += v2.y;
        }
        *(float2*)(sum_s + idx) = ss;
        *(float2*)(sum_v + idx) = sv;

        if (t >= 100 && ((t - 100) % 20) == 0) {
            const int k = (t - 100) / 20;
            const size_t oidx = (((size_t)b * 5 + (size_t)k) << 12) + n0;
            float* rates = out;
            float* vavg  = out + (size_t)NBATCH * 5 * NNEUR;
            float* srec  = out + (size_t)NBATCH * 5 * NNEUR * 2;
            *(float2*)(rates + oidx) = make_float2(ss.x / 20.f, ss.y / 20.f);
            *(float2*)(vavg  + oidx) = make_float2(sv.x / 20.f, sv.y / 20.f);
            *(float2*)(srec  + oidx) = s2;
        }
    }
}

extern "C" void kernel_launch(void* const* d_in, const int* in_sizes, int n_in,
                              void* d_out, int out_size, void* d_ws, size_t ws_size,
                              hipStream_t stream) {
    const float* ff   = (const float*)d_in[0];   // [128][200][4096] f32
    const float* W    = (const float*)d_in[1];   // [4096][4096] f32 (Wab_T)
    const float* rec0 = (const float*)d_in[2];   // [128][4096] f32
    float* out = (float*)d_out;                  // rates | volts_avg | spikes_rec

    char* ws = (char*)d_ws;
    const size_t STATE = (size_t)NBATCH * NNEUR * sizeof(float);   // 2 MB
    float* volts = (float*)(ws);
    float* rec   = (float*)(ws + STATE);
    float* sum_s = (float*)(ws + 2 * STATE);
    float* sum_v = (float*)(ws + 3 * STATE);
    unsigned long long* bits = (unsigned long long*)(ws + 4 * STATE);
    const int BWORDS = NBATCH * (NNEUR / 64);    // 8192 words per buffer

    for (int t = 0; t <= TLAST; ++t) {
        lif_step<<<dim3(1024), dim3(256), 0, stream>>>(
            ff, W, rec0, out, volts, rec, sum_s, sum_v,
            bits + (size_t)(t & 1) * BWORDS,
            bits + (size_t)((t + 1) & 1) * BWORDS, t);
    }
}